// Round 1
// 961.941 us; speedup vs baseline: 1.2631x; 1.2631x over previous
//
#include <hip/hip_runtime.h>

// B=2, S=2048, D=1024, H=16, Khid=64.  Inputs/outputs f32; MFMA compute bf16.
typedef unsigned short u16;
typedef unsigned long long u64;
typedef __attribute__((ext_vector_type(8))) short short8;   // 8 bf16 (4 VGPRs)
typedef __attribute__((ext_vector_type(8))) float float8;   // 32B
typedef __attribute__((ext_vector_type(4))) float floatx4;  // MFMA accumulator

__device__ __forceinline__ float bf2f(u16 b) { return __uint_as_float(((unsigned)b) << 16); }
__device__ __forceinline__ u16 f2bf(float f) {
    unsigned u = __float_as_uint(f);
    return (u16)((u + 0x7FFFu + ((u >> 16) & 1u)) >> 16);  // RNE
}

#define MFMA(a, b, c) __builtin_amdgcn_mfma_f32_16x16x32_bf16((a), (b), (c), 0, 0, 0)

// Padded LDS strides (u16 units) to kill ds_read_b128 bank conflicts:
// 32-wide tiles: stride 40 (80B rows, bank phase period 8 -> 2-way = free)
// 64-wide tiles: stride 72 (144B rows, (row+chunk)*4 %32 -> 2-way = free)
#define AST 40
#define KST 72

// ---------------------------------------------------------------------------
// Per-head projection of x (f32) with W[h] ([D,64] f32, n-contiguous), +bias.
// mode 0: out[(bh*2048+s)*64+n] bf16 (K)   mode 1: out[(bh*64+n)*2048+s] bf16 (V^T)
// grid (64, 16) x 256
__global__ __launch_bounds__(256) void k_proj_head(
    const float* __restrict__ x, const float* __restrict__ w, const float* __restrict__ bias,
    u16* __restrict__ out, int mode)
{
    int mt = blockIdx.x, h = blockIdx.y;
    int tid = threadIdx.x, wave = tid >> 6, lane = tid & 63;
    int col = lane & 15, quad = lane >> 4, m0 = wave * 16;
    int rg0 = mt * 64;

    __shared__ u16 As[64 * AST];
    __shared__ u16 Bs[64 * AST];

    floatx4 acc[4];
    for (int i = 0; i < 4; i++) acc[i] = (floatx4){0.f, 0.f, 0.f, 0.f};

    int lr = tid >> 2, lc = (tid & 3) * 8;   // As staging: 64 rows x 32 cols
    int dr = tid >> 3, nc = (tid & 7) * 8;   // Bs transpose staging: 32 d x 64 n
    const float* wh = w + (size_t)h * 65536;

    for (int dk = 0; dk < 1024; dk += 32) {
        float8 av = *(const float8*)&x[(size_t)(rg0 + lr) * 1024 + dk + lc];
        short8 a8;
        #pragma unroll
        for (int j = 0; j < 8; j++) a8[j] = (short)f2bf(av[j]);
        *(short8*)&As[lr * AST + lc] = a8;
        float8 wv = *(const float8*)&wh[(size_t)(dk + dr) * 64 + nc];
        #pragma unroll
        for (int j = 0; j < 8; j++) Bs[(nc + j) * AST + dr] = f2bf(wv[j]);
        __syncthreads();
        short8 a = *(const short8*)&As[(m0 + col) * AST + quad * 8];
        #pragma unroll
        for (int nt = 0; nt < 4; nt++) {
            short8 b = *(const short8*)&Bs[(nt * 16 + col) * AST + quad * 8];
            acc[nt] = MFMA(a, b, acc[nt]);
        }
        __syncthreads();
    }
    #pragma unroll
    for (int nt = 0; nt < 4; nt++) {
        int n = nt * 16 + col;
        float bv = bias[h * 64 + n];
        #pragma unroll
        for (int r = 0; r < 4; r++) {
            int rowl = m0 + quad * 4 + r;
            int rg = rg0 + rowl;
            int bb = rg >> 11, s = rg & 2047;
            size_t bh = (size_t)(bb * 16 + h);
            float v = acc[nt][r] + bv;
            if (mode == 0) out[(bh * 2048 + s) * 64 + n] = f2bf(v);
            else           out[(bh * 64 + n) * 2048 + s] = f2bf(v);
        }
    }
}

// ---------------------------------------------------------------------------
// Pack mask [2,2048,2048] i32 -> transposed bitmask bits[(b*32+w)*2048+s],
// bit j of word w = (mask[b][s][w*64+j] != 0).   grid (4096) x 256
__global__ __launch_bounds__(256) void k_pack(
    const int* __restrict__ mask, u64* __restrict__ bits)
{
    int row = blockIdx.x;              // b*2048 + s
    int b = row >> 11, s = row & 2047;
    int wv = threadIdx.x >> 6, lane = threadIdx.x & 63;
    for (int w = wv; w < 32; w += 4) {
        int m = mask[(size_t)row * 2048 + w * 64 + lane];
        u64 bal = __ballot(m != 0);
        if (lane == 0) bits[((size_t)(b * 32 + w)) * 2048 + s] = bal;
    }
}

// ---------------------------------------------------------------------------
// Fused scores+softmax+PV. Per (bh, 64-row s-tile):
//  Phase 0: Q tile on the fly (x*W_Q[h]+b_Q, bf16) -> LDS -> A-fragments.
//  Pass 1:  QK^T tiles -> masked row max/sum-exp (register shuffle reduce).
//  Pass 2:  recompute QK^T (bit-identical), p=exp(s-m)/l, write p (final
//           attn_scores), bf16 P tile in LDS, PV MFMA -> concat bf16.
// grid (32, 32) x 256
__global__ __launch_bounds__(256, 4) void k_fused(
    const float* __restrict__ x, const float* __restrict__ wq, const float* __restrict__ bq,
    const u16* __restrict__ Kbuf, const u16* __restrict__ Vt,
    const u64* __restrict__ mbits,
    float* __restrict__ sc, u16* __restrict__ concat)
{
    int st = blockIdx.x, bh = blockIdx.y;
    int b = bh >> 4, h = bh & 15;
    int s0 = st * 64;
    int tid = threadIdx.x, wave = tid >> 6, lane = tid & 63;
    int col = lane & 15, quad = lane >> 4, m0 = wave * 16;

    // LDS pool: 3 x 64*KST u16 tiles (9216B each), aliased:
    //   Ks (pass K tile | phase0 As), Vs (pass2 V tile | phase0 Bs),
    //   Ps (pass2 P tile | phase0 Qs)
    __shared__ __align__(16) char pool[3 * 64 * KST * 2];
    u16* Ks = (u16*)pool;
    u16* Vs = (u16*)(pool + 64 * KST * 2);
    u16* Ps = (u16*)(pool + 2 * 64 * KST * 2);
    u16* As = Ks;
    u16* Bs = Vs;
    u16* Qs = Ps;
    __shared__ u64 Mw[64];
    __shared__ float mrun[64], lrun[64];

    // ---- Phase 0: Q tile ----
    floatx4 acc[4];
    for (int i = 0; i < 4; i++) acc[i] = (floatx4){0.f, 0.f, 0.f, 0.f};
    int lr = tid >> 2, lc = (tid & 3) * 8;
    int dr = tid >> 3, nc = (tid & 7) * 8;
    const float* wh = wq + (size_t)h * 65536;
    const float* xb = x + ((size_t)b * 2048 + s0) * 1024;

    for (int dk = 0; dk < 1024; dk += 32) {
        float8 av = *(const float8*)&xb[(size_t)lr * 1024 + dk + lc];
        short8 a8;
        #pragma unroll
        for (int j = 0; j < 8; j++) a8[j] = (short)f2bf(av[j]);
        *(short8*)&As[lr * AST + lc] = a8;
        float8 wv = *(const float8*)&wh[(size_t)(dk + dr) * 64 + nc];
        #pragma unroll
        for (int j = 0; j < 8; j++) Bs[(nc + j) * AST + dr] = f2bf(wv[j]);
        __syncthreads();
        short8 a = *(const short8*)&As[(m0 + col) * AST + quad * 8];
        #pragma unroll
        for (int nt = 0; nt < 4; nt++) {
            short8 b2 = *(const short8*)&Bs[(nt * 16 + col) * AST + quad * 8];
            acc[nt] = MFMA(a, b2, acc[nt]);
        }
        __syncthreads();
    }
    if (tid < 64) { mrun[tid] = -1e30f; lrun[tid] = 0.f; }
    #pragma unroll
    for (int nt = 0; nt < 4; nt++) {
        int n = nt * 16 + col;
        float bv = bq[h * 64 + n];
        #pragma unroll
        for (int r = 0; r < 4; r++) {
            int rowl = m0 + quad * 4 + r;
            Qs[rowl * KST + n] = f2bf(acc[nt][r] + bv);
        }
    }
    __syncthreads();
    short8 aq0 = *(const short8*)&Qs[(m0 + col) * KST + quad * 8];
    short8 aq1 = *(const short8*)&Qs[(m0 + col) * KST + 32 + quad * 8];

    const u16* Kh = Kbuf + (size_t)bh * 2048 * 64;
    const u16* Vh = Vt + (size_t)bh * 64 * 2048;
    const u64* mrow = mbits + (size_t)b * 32 * 2048;
    int srow = tid >> 3, soff = (tid & 7) * 8;

    // ---- Pass 1: stats only ----
    for (int t0 = 0; t0 < 2048; t0 += 64) {
        *(short8*)&Ks[srow * KST + soff]        = *(const short8*)&Kh[(size_t)(t0 + srow) * 64 + soff];
        *(short8*)&Ks[(srow + 32) * KST + soff] = *(const short8*)&Kh[(size_t)(t0 + srow + 32) * 64 + soff];
        if (tid < 64) Mw[tid] = mrow[(size_t)(t0 >> 6) * 2048 + s0 + tid];
        __syncthreads();
        floatx4 c4[4];
        #pragma unroll
        for (int nt = 0; nt < 4; nt++) {
            c4[nt] = (floatx4){0.f, 0.f, 0.f, 0.f};
            short8 b0 = *(const short8*)&Ks[(nt * 16 + col) * KST + quad * 8];
            short8 b1 = *(const short8*)&Ks[(nt * 16 + col) * KST + 32 + quad * 8];
            c4[nt] = MFMA(aq0, b0, c4[nt]);
            c4[nt] = MFMA(aq1, b1, c4[nt]);
        }
        #pragma unroll
        for (int r = 0; r < 4; r++) {
            int rowl = m0 + quad * 4 + r;
            u64 mw = Mw[rowl];
            float vv[4];
            float tm = -1e30f;
            #pragma unroll
            for (int nt = 0; nt < 4; nt++) {
                bool on = (mw >> (nt * 16 + col)) & 1ull;
                float v = on ? c4[nt][r] * 0.125f : -1e30f;
                vv[nt] = v;
                tm = fmaxf(tm, v);
            }
            tm = fmaxf(tm, __shfl_xor(tm, 1, 64));
            tm = fmaxf(tm, __shfl_xor(tm, 2, 64));
            tm = fmaxf(tm, __shfl_xor(tm, 4, 64));
            tm = fmaxf(tm, __shfl_xor(tm, 8, 64));
            float ts = 0.f;
            #pragma unroll
            for (int nt = 0; nt < 4; nt++)
                ts += (vv[nt] > -0.9e30f) ? __expf(vv[nt] - tm) : 0.f;
            ts += __shfl_xor(ts, 1, 64);
            ts += __shfl_xor(ts, 2, 64);
            ts += __shfl_xor(ts, 4, 64);
            ts += __shfl_xor(ts, 8, 64);
            if (col == 0 && tm > -0.9e30f) {
                float om = mrun[rowl];
                float nm = fmaxf(om, tm);
                lrun[rowl] = lrun[rowl] * __expf(om - nm) + ts * __expf(tm - nm);
                mrun[rowl] = nm;
            }
        }
        __syncthreads();
    }

    // ---- Pass 2: recompute, normalize, write p, PV ----
    float mreg[4], rlreg[4];
    #pragma unroll
    for (int r = 0; r < 4; r++) {
        int rowl = m0 + quad * 4 + r;
        mreg[r] = mrun[rowl];
        float l = lrun[rowl];
        rlreg[r] = (l > 0.f) ? 1.0f / l : 0.f;
    }
    floatx4 accp[4];
    for (int i = 0; i < 4; i++) accp[i] = (floatx4){0.f, 0.f, 0.f, 0.f};
    float* scb = sc + (size_t)bh * 2048 * 2048;

    for (int t0 = 0; t0 < 2048; t0 += 64) {
        *(short8*)&Ks[srow * KST + soff]        = *(const short8*)&Kh[(size_t)(t0 + srow) * 64 + soff];
        *(short8*)&Ks[(srow + 32) * KST + soff] = *(const short8*)&Kh[(size_t)(t0 + srow + 32) * 64 + soff];
        *(short8*)&Vs[srow * KST + soff]        = *(const short8*)&Vh[(size_t)srow * 2048 + t0 + soff];
        *(short8*)&Vs[(srow + 32) * KST + soff] = *(const short8*)&Vh[(size_t)(srow + 32) * 2048 + t0 + soff];
        if (tid < 64) Mw[tid] = mrow[(size_t)(t0 >> 6) * 2048 + s0 + tid];
        __syncthreads();
        floatx4 c4[4];
        #pragma unroll
        for (int nt = 0; nt < 4; nt++) {
            c4[nt] = (floatx4){0.f, 0.f, 0.f, 0.f};
            short8 b0 = *(const short8*)&Ks[(nt * 16 + col) * KST + quad * 8];
            short8 b1 = *(const short8*)&Ks[(nt * 16 + col) * KST + 32 + quad * 8];
            c4[nt] = MFMA(aq0, b0, c4[nt]);
            c4[nt] = MFMA(aq1, b1, c4[nt]);
        }
        #pragma unroll
        for (int r = 0; r < 4; r++) {
            int rowl = m0 + quad * 4 + r;
            u64 mw = Mw[rowl];
            size_t base = (size_t)(s0 + rowl) * 2048 + t0;
            #pragma unroll
            for (int nt = 0; nt < 4; nt++) {
                bool on = (mw >> (nt * 16 + col)) & 1ull;
                float p = on ? __expf(c4[nt][r] * 0.125f - mreg[r]) * rlreg[r] : 0.f;
                scb[base + nt * 16 + col] = p;
                Ps[rowl * KST + nt * 16 + col] = f2bf(p);
            }
        }
        __syncthreads();
        short8 ap0 = *(const short8*)&Ps[(m0 + col) * KST + quad * 8];
        short8 ap1 = *(const short8*)&Ps[(m0 + col) * KST + 32 + quad * 8];
        #pragma unroll
        for (int nt = 0; nt < 4; nt++) {
            short8 b0 = *(const short8*)&Vs[(nt * 16 + col) * KST + quad * 8];
            short8 b1 = *(const short8*)&Vs[(nt * 16 + col) * KST + 32 + quad * 8];
            accp[nt] = MFMA(ap0, b0, accp[nt]);
            accp[nt] = MFMA(ap1, b1, accp[nt]);
        }
        __syncthreads();
    }
    #pragma unroll
    for (int nt = 0; nt < 4; nt++) {
        int n = nt * 16 + col;
        #pragma unroll
        for (int r = 0; r < 4; r++) {
            int rowl = m0 + quad * 4 + r;
            concat[((size_t)(b * 2048 + s0 + rowl)) * 1024 + h * 64 + n] = f2bf(accp[nt][r]);
        }
    }
}

// ---------------------------------------------------------------------------
// Output projection: out f32 = concat(bf16) @ W_proj(f32) + b_proj.
// grid (64, 16) x 256
__global__ __launch_bounds__(256) void k_out(
    const u16* __restrict__ concat, const float* __restrict__ wp,
    const float* __restrict__ bp, float* __restrict__ outp)
{
    int mt = blockIdx.x, ntile = blockIdx.y;
    int n0 = ntile * 64;
    int tid = threadIdx.x, wave = tid >> 6, lane = tid & 63;
    int col = lane & 15, quad = lane >> 4, m0 = wave * 16;
    int rg0 = mt * 64;

    __shared__ u16 As[64 * AST];
    __shared__ u16 Bs[64 * AST];

    floatx4 acc[4];
    for (int i = 0; i < 4; i++) acc[i] = (floatx4){0.f, 0.f, 0.f, 0.f};

    int lr = tid >> 2, lc = (tid & 3) * 8;
    int cr = tid >> 3, nc = (tid & 7) * 8;
    for (int c = 0; c < 1024; c += 32) {
        *(short8*)&As[lr * AST + lc] = *(const short8*)&concat[(size_t)(rg0 + lr) * 1024 + c + lc];
        float8 wv = *(const float8*)&wp[(size_t)(c + cr) * 1024 + n0 + nc];
        #pragma unroll
        for (int j = 0; j < 8; j++) Bs[(nc + j) * AST + cr] = f2bf(wv[j]);
        __syncthreads();
        short8 a = *(const short8*)&As[(m0 + col) * AST + quad * 8];
        #pragma unroll
        for (int nt = 0; nt < 4; nt++) {
            short8 b = *(const short8*)&Bs[(nt * 16 + col) * AST + quad * 8];
            acc[nt] = MFMA(a, b, acc[nt]);
        }
        __syncthreads();
    }
    #pragma unroll
    for (int nt = 0; nt < 4; nt++) {
        int n = n0 + nt * 16 + col;
        float bv = bp[n];
        #pragma unroll
        for (int r = 0; r < 4; r++) {
            int rowl = m0 + quad * 4 + r;
            outp[(size_t)(rg0 + rowl) * 1024 + n] = acc[nt][r] + bv;
        }
    }
}

// ---------------------------------------------------------------------------
extern "C" void kernel_launch(void* const* d_in, const int* in_sizes, int n_in,
                              void* d_out, int out_size, void* d_ws, size_t ws_size,
                              hipStream_t stream) {
    const float* x  = (const float*)d_in[0];
    const float* WQ = (const float*)d_in[1];
    const float* bQ = (const float*)d_in[2];
    const float* WK = (const float*)d_in[3];
    const float* bK = (const float*)d_in[4];
    const float* WV = (const float*)d_in[5];
    const float* bV = (const float*)d_in[6];
    const float* WP = (const float*)d_in[7];
    const float* bP = (const float*)d_in[8];
    const int* mask = (const int*)d_in[9];

    float* out = (float*)d_out;
    float* attn_out = out;                     // [2,2048,1024] f32 = 4,194,304 elems
    float* sc = out + (size_t)4194304;         // [2,16,2048,2048] f32

    const size_t NEED = (size_t)3 * 8388608 + 1048576;  // K,Vt,concat bf16 + bitmask
    u16 *Kbuf, *Vtb, *concat;
    u64* mbits;
    if (ws_size >= NEED) {
        char* ws = (char*)d_ws;
        Kbuf   = (u16*)ws;               ws += 8388608;
        Vtb    = (u16*)ws;               ws += 8388608;
        concat = (u16*)ws;               ws += 8388608;
        mbits  = (u64*)ws;
    } else {
        // Fallback (deterministic across calls): K|Vt overlay the dead
        // attn_out region (16.78MB, written last); bitmask in dead W_K buffer
        // (packed AFTER k_proj reads W_K); concat in dead mask buffer (written
        // AFTER k_pack reads mask).
        Kbuf   = (u16*)attn_out;
        Vtb    = Kbuf + (size_t)4194304;
        mbits  = (u64*)d_in[3];
        concat = (u16*)d_in[9];
    }

    k_proj_head<<<dim3(64, 16), 256, 0, stream>>>(x, WK, bK, Kbuf, 0);     // K
    k_proj_head<<<dim3(64, 16), 256, 0, stream>>>(x, WV, bV, Vtb, 1);      // V^T
    k_pack<<<dim3(4096), 256, 0, stream>>>(mask, mbits);
    k_fused<<<dim3(32, 32), 256, 0, stream>>>(x, WQ, bQ, Kbuf, Vtb, mbits, sc, concat);
    k_out<<<dim3(64, 16), 256, 0, stream>>>(concat, WP, bP, attn_out);
}

// Round 2
// 853.824 us; speedup vs baseline: 1.4230x; 1.1266x over previous
//
#include <hip/hip_runtime.h>

// B=2, S=2048, D=1024, H=16, Khid=64.  Inputs/outputs f32; MFMA compute bf16.
typedef unsigned short u16;
typedef unsigned long long u64;
typedef __attribute__((ext_vector_type(8))) short short8;   // 8 bf16 (4 VGPRs)
typedef __attribute__((ext_vector_type(8))) float float8;   // 32B
typedef __attribute__((ext_vector_type(4))) float floatx4;  // MFMA accumulator

__device__ __forceinline__ u16 f2bf(float f) {
    unsigned u = __float_as_uint(f);
    return (u16)((u + 0x7FFFu + ((u >> 16) & 1u)) >> 16);  // RNE
}

#define MFMA(a, b, c) __builtin_amdgcn_mfma_f32_16x16x32_bf16((a), (b), (c), 0, 0, 0)

// Padded LDS strides (u16 units) to kill ds_read_b128 bank conflicts:
// 32-wide tiles: stride 40 (80B rows) -> 2-way = free
// 64-wide tiles: stride 72 (144B rows) -> 2-way = free
#define AST 40
#define KST 72

// ---------------------------------------------------------------------------
// Merged K+V projection: K -> Kbuf[bh][s][64] bf16, V^T -> Vt[bh][n][2048] bf16.
// Shares the x A-tile between both GEMMs; V^T store goes through an LDS
// transpose for 32B-coalesced rows.  grid (64, 16) x 256
__global__ __launch_bounds__(256) void k_projkv(
    const float* __restrict__ x,
    const float* __restrict__ wk, const float* __restrict__ bk,
    const float* __restrict__ wv, const float* __restrict__ bv,
    u16* __restrict__ Kout, u16* __restrict__ Vout)
{
    int mt = blockIdx.x, h = blockIdx.y;
    int tid = threadIdx.x, wave = tid >> 6, lane = tid & 63;
    int col = lane & 15, quad = lane >> 4, m0 = wave * 16;
    int rg0 = mt * 64;

    __shared__ __align__(16) char pool[3 * 64 * AST * 2];   // 15360B
    u16* As = (u16*)pool;
    u16* Bk = (u16*)(pool + 64 * AST * 2);
    u16* Bv = (u16*)(pool + 2 * 64 * AST * 2);

    floatx4 accK[4], accV[4];
    for (int i = 0; i < 4; i++) { accK[i] = (floatx4){0,0,0,0}; accV[i] = (floatx4){0,0,0,0}; }

    int lr = tid >> 2, lc = (tid & 3) * 8;   // As staging: 64 rows x 32 cols
    int dr = tid >> 3, nc = (tid & 7) * 8;   // B transpose staging: 32 d x 64 n
    const float* whk = wk + (size_t)h * 65536;
    const float* whv = wv + (size_t)h * 65536;

    float8 av = *(const float8*)&x[(size_t)(rg0 + lr) * 1024 + lc];
    float8 wkp = *(const float8*)&whk[(size_t)dr * 64 + nc];
    float8 wvp = *(const float8*)&whv[(size_t)dr * 64 + nc];

    for (int dk = 0; dk < 1024; dk += 32) {
        short8 a8;
        #pragma unroll
        for (int j = 0; j < 8; j++) a8[j] = (short)f2bf(av[j]);
        *(short8*)&As[lr * AST + lc] = a8;
        #pragma unroll
        for (int j = 0; j < 8; j++) Bk[(nc + j) * AST + dr] = f2bf(wkp[j]);
        #pragma unroll
        for (int j = 0; j < 8; j++) Bv[(nc + j) * AST + dr] = f2bf(wvp[j]);
        __syncthreads();
        if (dk + 32 < 1024) {
            av  = *(const float8*)&x[(size_t)(rg0 + lr) * 1024 + dk + 32 + lc];
            wkp = *(const float8*)&whk[(size_t)(dk + 32 + dr) * 64 + nc];
            wvp = *(const float8*)&whv[(size_t)(dk + 32 + dr) * 64 + nc];
        }
        short8 a = *(const short8*)&As[(m0 + col) * AST + quad * 8];
        #pragma unroll
        for (int nt = 0; nt < 4; nt++) {
            short8 bkf = *(const short8*)&Bk[(nt * 16 + col) * AST + quad * 8];
            short8 bvf = *(const short8*)&Bv[(nt * 16 + col) * AST + quad * 8];
            accK[nt] = MFMA(a, bkf, accK[nt]);
            accV[nt] = MFMA(a, bvf, accV[nt]);
        }
        __syncthreads();
    }

    int bb = rg0 >> 11, s0 = rg0 & 2047;
    size_t bh = (size_t)(bb * 16 + h);

    // K: direct store (32B segments per 16 lanes)
    #pragma unroll
    for (int nt = 0; nt < 4; nt++) {
        int n = nt * 16 + col;
        float bvl = bk[h * 64 + n];
        #pragma unroll
        for (int r = 0; r < 4; r++) {
            int rowl = m0 + quad * 4 + r;
            Kout[(bh * 2048 + s0 + rowl) * 64 + n] = f2bf(accK[nt][r] + bvl);
        }
    }

    // V: LDS transpose -> coalesced 32B/lane rows
    u16* VT = (u16*)pool;   // [64 n][stride 68], 8704B <= pool
    #pragma unroll
    for (int nt = 0; nt < 4; nt++) {
        int n = nt * 16 + col;
        float bvl = bv[h * 64 + n];
        #pragma unroll
        for (int r = 0; r < 4; r++) {
            int rowl = m0 + quad * 4 + r;
            VT[n * 68 + rowl] = f2bf(accV[nt][r] + bvl);
        }
    }
    __syncthreads();
    {
        int n2 = tid >> 2, sseg = (tid & 3) * 16;
        short8 p0 = *(const short8*)&VT[n2 * 68 + sseg];
        short8 p1 = *(const short8*)&VT[n2 * 68 + sseg + 8];
        u16* dst = &Vout[(bh * 64 + n2) * 2048 + s0 + sseg];
        *(short8*)dst = p0;
        *(short8*)(dst + 8) = p1;
    }
}

// ---------------------------------------------------------------------------
// Pack mask [2,2048,2048] i32 -> transposed bitmask bits[(b*32+w)*2048+s],
// bit j of word w = (mask[b][s][w*64+j] != 0).   grid (4096) x 256
__global__ __launch_bounds__(256) void k_pack(
    const int* __restrict__ mask, u64* __restrict__ bits)
{
    int row = blockIdx.x;              // b*2048 + s
    int b = row >> 11, s = row & 2047;
    int wv = threadIdx.x >> 6, lane = threadIdx.x & 63;
    for (int w = wv; w < 32; w += 4) {
        int m = mask[(size_t)row * 2048 + w * 64 + lane];
        u64 bal = __ballot(m != 0);
        if (lane == 0) bits[((size_t)(b * 32 + w)) * 2048 + s] = bal;
    }
}

// ---------------------------------------------------------------------------
// Fused scores+softmax+PV. Per (bh, 64-row s-tile):
//  Phase 0: Q tile on the fly (x*W_Q[h]+b_Q, bf16) -> LDS.
//  Pass 1:  SWAPPED QK^T (D = K·Q^T, t lane-local) -> register-online (m,l):
//           16 local fmax/exp + 2 shuffles per tile, no LDS RMW.
//  Pass 2:  normal-orientation recompute, p=exp(s-m)/l, write p (final
//           attn_scores, 64B segments), bf16 P tile in LDS, PV MFMA -> concat.
//  K/V tiles register-prefetched (T14) in both passes.
// grid (32, 32) x 256
__global__ __launch_bounds__(256, 4) void k_fused(
    const float* __restrict__ x, const float* __restrict__ wq, const float* __restrict__ bq,
    const u16* __restrict__ Kbuf, const u16* __restrict__ Vt,
    const u64* __restrict__ mbits,
    float* __restrict__ sc, u16* __restrict__ concat)
{
    int st = blockIdx.x, bh = blockIdx.y;
    int b = bh >> 4, h = bh & 15;
    int s0 = st * 64;
    int tid = threadIdx.x, wave = tid >> 6, lane = tid & 63;
    int col = lane & 15, quad = lane >> 4, m0 = wave * 16;

    // LDS pool: 3 x 64*KST u16 tiles (9216B each), aliased:
    //   Ks (pass K tile | phase0 As), Vs (pass2 V tile | phase0 Bs),
    //   Ps (pass2 P tile | phase0 Qs)
    __shared__ __align__(16) char pool[3 * 64 * KST * 2];
    u16* Ks = (u16*)pool;
    u16* Vs = (u16*)(pool + 64 * KST * 2);
    u16* Ps = (u16*)(pool + 2 * 64 * KST * 2);
    u16* As = Ks;
    u16* Bs = Vs;
    u16* Qs = Ps;
    __shared__ u64 Mw[64];
    __shared__ float mrun[64], lrun[64];

    // ---- Phase 0: Q tile ----
    floatx4 acc[4];
    for (int i = 0; i < 4; i++) acc[i] = (floatx4){0,0,0,0};
    int lr = tid >> 2, lc = (tid & 3) * 8;
    int dr = tid >> 3, nc = (tid & 7) * 8;
    const float* wh = wq + (size_t)h * 65536;
    const float* xb = x + ((size_t)b * 2048 + s0) * 1024;

    {
        float8 av = *(const float8*)&xb[(size_t)lr * 1024 + lc];
        float8 wv = *(const float8*)&wh[(size_t)dr * 64 + nc];
        for (int dk = 0; dk < 1024; dk += 32) {
            short8 a8;
            #pragma unroll
            for (int j = 0; j < 8; j++) a8[j] = (short)f2bf(av[j]);
            *(short8*)&As[lr * AST + lc] = a8;
            #pragma unroll
            for (int j = 0; j < 8; j++) Bs[(nc + j) * AST + dr] = f2bf(wv[j]);
            __syncthreads();
            if (dk + 32 < 1024) {
                av = *(const float8*)&xb[(size_t)lr * 1024 + dk + 32 + lc];
                wv = *(const float8*)&wh[(size_t)(dk + 32 + dr) * 64 + nc];
            }
            short8 a = *(const short8*)&As[(m0 + col) * AST + quad * 8];
            #pragma unroll
            for (int nt = 0; nt < 4; nt++) {
                short8 b2 = *(const short8*)&Bs[(nt * 16 + col) * AST + quad * 8];
                acc[nt] = MFMA(a, b2, acc[nt]);
            }
            __syncthreads();
        }
    }
    #pragma unroll
    for (int nt = 0; nt < 4; nt++) {
        int n = nt * 16 + col;
        float bvq = bq[h * 64 + n];
        #pragma unroll
        for (int r = 0; r < 4; r++) {
            int rowl = m0 + quad * 4 + r;
            Qs[rowl * KST + n] = f2bf(acc[nt][r] + bvq);
        }
    }
    __syncthreads();
    short8 aq0 = *(const short8*)&Qs[(m0 + col) * KST + quad * 8];
    short8 aq1 = *(const short8*)&Qs[(m0 + col) * KST + 32 + quad * 8];

    const u16* Kh = Kbuf + (size_t)bh * 2048 * 64;
    const u16* Vh = Vt + (size_t)bh * 64 * 2048;
    const u64* mrow = mbits + (size_t)b * 32 * 2048;
    int srow = tid >> 3, soff = (tid & 7) * 8;

    // ---- Pass 1: stats only (swapped operands, register softmax) ----
    float mreg = -1e30f, lreg = 0.f;   // stats for s = s0 + m0 + col
    {
        short8 kp0 = *(const short8*)&Kh[(size_t)srow * 64 + soff];
        short8 kp1 = *(const short8*)&Kh[(size_t)(srow + 32) * 64 + soff];
        for (int t0 = 0; t0 < 2048; t0 += 64) {
            *(short8*)&Ks[srow * KST + soff]        = kp0;
            *(short8*)&Ks[(srow + 32) * KST + soff] = kp1;
            if (tid < 64) Mw[tid] = mrow[(size_t)(t0 >> 6) * 2048 + s0 + tid];
            __syncthreads();
            if (t0 + 64 < 2048) {
                kp0 = *(const short8*)&Kh[(size_t)(t0 + 64 + srow) * 64 + soff];
                kp1 = *(const short8*)&Kh[(size_t)(t0 + 64 + srow + 32) * 64 + soff];
            }
            floatx4 c4[4];
            #pragma unroll
            for (int nt = 0; nt < 4; nt++) {
                c4[nt] = (floatx4){0,0,0,0};
                short8 b0 = *(const short8*)&Ks[(nt * 16 + col) * KST + quad * 8];
                short8 b1 = *(const short8*)&Ks[(nt * 16 + col) * KST + 32 + quad * 8];
                c4[nt] = MFMA(b0, aq0, c4[nt]);   // D[t][s]: t lane-local
                c4[nt] = MFMA(b1, aq1, c4[nt]);
            }
            u64 mw = Mw[m0 + col];
            float tm = -1e30f;
            #pragma unroll
            for (int nt = 0; nt < 4; nt++)
                #pragma unroll
                for (int r = 0; r < 4; r++) {
                    bool on = (mw >> (nt * 16 + quad * 4 + r)) & 1ull;
                    float v = on ? c4[nt][r] * 0.125f : -1e30f;
                    tm = fmaxf(tm, v);
                }
            tm = fmaxf(tm, __shfl_xor(tm, 16, 64));
            tm = fmaxf(tm, __shfl_xor(tm, 32, 64));
            float ts = 0.f;
            #pragma unroll
            for (int nt = 0; nt < 4; nt++)
                #pragma unroll
                for (int r = 0; r < 4; r++) {
                    bool on = (mw >> (nt * 16 + quad * 4 + r)) & 1ull;
                    ts += on ? __expf(c4[nt][r] * 0.125f - tm) : 0.f;
                }
            ts += __shfl_xor(ts, 16, 64);
            ts += __shfl_xor(ts, 32, 64);
            if (tm > -0.9e30f) {
                float nm = fmaxf(mreg, tm);
                lreg = lreg * __expf(mreg - nm) + ts * __expf(tm - nm);
                mreg = nm;
            }
            __syncthreads();
        }
    }
    if (quad == 0) { mrun[m0 + col] = mreg; lrun[m0 + col] = lreg; }
    __syncthreads();

    // ---- Pass 2: recompute (normal orientation), normalize, write p, PV ----
    float mr4[4], rl4[4];
    #pragma unroll
    for (int r = 0; r < 4; r++) {
        int rowl = m0 + quad * 4 + r;
        mr4[r] = mrun[rowl];
        float l = lrun[rowl];
        rl4[r] = (l > 0.f) ? 1.0f / l : 0.f;
    }
    floatx4 accp[4];
    for (int i = 0; i < 4; i++) accp[i] = (floatx4){0,0,0,0};
    float* scb = sc + (size_t)bh * 2048 * 2048;

    {
        short8 kp0 = *(const short8*)&Kh[(size_t)srow * 64 + soff];
        short8 kp1 = *(const short8*)&Kh[(size_t)(srow + 32) * 64 + soff];
        short8 vp0 = *(const short8*)&Vh[(size_t)srow * 2048 + soff];
        short8 vp1 = *(const short8*)&Vh[(size_t)(srow + 32) * 2048 + soff];
        for (int t0 = 0; t0 < 2048; t0 += 64) {
            *(short8*)&Ks[srow * KST + soff]        = kp0;
            *(short8*)&Ks[(srow + 32) * KST + soff] = kp1;
            *(short8*)&Vs[srow * KST + soff]        = vp0;
            *(short8*)&Vs[(srow + 32) * KST + soff] = vp1;
            if (tid < 64) Mw[tid] = mrow[(size_t)(t0 >> 6) * 2048 + s0 + tid];
            __syncthreads();
            if (t0 + 64 < 2048) {
                kp0 = *(const short8*)&Kh[(size_t)(t0 + 64 + srow) * 64 + soff];
                kp1 = *(const short8*)&Kh[(size_t)(t0 + 64 + srow + 32) * 64 + soff];
                vp0 = *(const short8*)&Vh[(size_t)srow * 2048 + t0 + 64 + soff];
                vp1 = *(const short8*)&Vh[(size_t)(srow + 32) * 2048 + t0 + 64 + soff];
            }
            floatx4 c4[4];
            #pragma unroll
            for (int nt = 0; nt < 4; nt++) {
                c4[nt] = (floatx4){0,0,0,0};
                short8 b0 = *(const short8*)&Ks[(nt * 16 + col) * KST + quad * 8];
                short8 b1 = *(const short8*)&Ks[(nt * 16 + col) * KST + 32 + quad * 8];
                c4[nt] = MFMA(aq0, b0, c4[nt]);
                c4[nt] = MFMA(aq1, b1, c4[nt]);
            }
            #pragma unroll
            for (int r = 0; r < 4; r++) {
                int rowl = m0 + quad * 4 + r;
                u64 mw = Mw[rowl];
                size_t base = (size_t)(s0 + rowl) * 2048 + t0;
                #pragma unroll
                for (int nt = 0; nt < 4; nt++) {
                    bool on = (mw >> (nt * 16 + col)) & 1ull;
                    float p = on ? __expf(c4[nt][r] * 0.125f - mr4[r]) * rl4[r] : 0.f;
                    scb[base + nt * 16 + col] = p;
                    Ps[rowl * KST + nt * 16 + col] = f2bf(p);
                }
            }
            __syncthreads();
            short8 ap0 = *(const short8*)&Ps[(m0 + col) * KST + quad * 8];
            short8 ap1 = *(const short8*)&Ps[(m0 + col) * KST + 32 + quad * 8];
            #pragma unroll
            for (int nt = 0; nt < 4; nt++) {
                short8 b0 = *(const short8*)&Vs[(nt * 16 + col) * KST + quad * 8];
                short8 b1 = *(const short8*)&Vs[(nt * 16 + col) * KST + 32 + quad * 8];
                accp[nt] = MFMA(ap0, b0, accp[nt]);
                accp[nt] = MFMA(ap1, b1, accp[nt]);
            }
            __syncthreads();
        }
    }
    #pragma unroll
    for (int nt = 0; nt < 4; nt++) {
        int n = nt * 16 + col;
        #pragma unroll
        for (int r = 0; r < 4; r++) {
            int rowl = m0 + quad * 4 + r;
            concat[((size_t)(b * 2048 + s0 + rowl)) * 1024 + h * 64 + n] = f2bf(accp[nt][r]);
        }
    }
}

// ---------------------------------------------------------------------------
// Output projection: out f32 = concat(bf16) @ W_proj(f32) + b_proj.
// grid (64, 16) x 256
__global__ __launch_bounds__(256) void k_out(
    const u16* __restrict__ concat, const float* __restrict__ wp,
    const float* __restrict__ bp, float* __restrict__ outp)
{
    int mt = blockIdx.x, ntile = blockIdx.y;
    int n0 = ntile * 64;
    int tid = threadIdx.x, wave = tid >> 6, lane = tid & 63;
    int col = lane & 15, quad = lane >> 4, m0 = wave * 16;
    int rg0 = mt * 64;

    __shared__ u16 As[64 * AST];
    __shared__ u16 Bs[64 * AST];

    floatx4 acc[4];
    for (int i = 0; i < 4; i++) acc[i] = (floatx4){0,0,0,0};

    int lr = tid >> 2, lc = (tid & 3) * 8;
    int cr = tid >> 3, nc = (tid & 7) * 8;
    short8 ap = *(const short8*)&concat[(size_t)(rg0 + lr) * 1024 + lc];
    float8 wv = *(const float8*)&wp[(size_t)cr * 1024 + n0 + nc];
    for (int c = 0; c < 1024; c += 32) {
        *(short8*)&As[lr * AST + lc] = ap;
        #pragma unroll
        for (int j = 0; j < 8; j++) Bs[(nc + j) * AST + cr] = f2bf(wv[j]);
        __syncthreads();
        if (c + 32 < 1024) {
            ap = *(const short8*)&concat[(size_t)(rg0 + lr) * 1024 + c + 32 + lc];
            wv = *(const float8*)&wp[(size_t)(c + 32 + cr) * 1024 + n0 + nc];
        }
        short8 a = *(const short8*)&As[(m0 + col) * AST + quad * 8];
        #pragma unroll
        for (int nt = 0; nt < 4; nt++) {
            short8 b = *(const short8*)&Bs[(nt * 16 + col) * AST + quad * 8];
            acc[nt] = MFMA(a, b, acc[nt]);
        }
        __syncthreads();
    }
    #pragma unroll
    for (int nt = 0; nt < 4; nt++) {
        int n = n0 + nt * 16 + col;
        float bv = bp[n];
        #pragma unroll
        for (int r = 0; r < 4; r++) {
            int rowl = m0 + quad * 4 + r;
            outp[(size_t)(rg0 + rowl) * 1024 + n] = acc[nt][r] + bv;
        }
    }
}

// ---------------------------------------------------------------------------
extern "C" void kernel_launch(void* const* d_in, const int* in_sizes, int n_in,
                              void* d_out, int out_size, void* d_ws, size_t ws_size,
                              hipStream_t stream) {
    const float* x  = (const float*)d_in[0];
    const float* WQ = (const float*)d_in[1];
    const float* bQ = (const float*)d_in[2];
    const float* WK = (const float*)d_in[3];
    const float* bK = (const float*)d_in[4];
    const float* WV = (const float*)d_in[5];
    const float* bV = (const float*)d_in[6];
    const float* WP = (const float*)d_in[7];
    const float* bP = (const float*)d_in[8];
    const int* mask = (const int*)d_in[9];

    float* out = (float*)d_out;
    float* attn_out = out;                     // [2,2048,1024] f32 = 4,194,304 elems
    float* sc = out + (size_t)4194304;         // [2,16,2048,2048] f32

    const size_t NEED = (size_t)3 * 8388608 + 1048576;  // K,Vt,concat bf16 + bitmask
    u16 *Kbuf, *Vtb, *concat;
    u64* mbits;
    if (ws_size >= NEED) {
        char* ws = (char*)d_ws;
        Kbuf   = (u16*)ws;               ws += 8388608;
        Vtb    = (u16*)ws;               ws += 8388608;
        concat = (u16*)ws;               ws += 8388608;
        mbits  = (u64*)ws;
    } else {
        // Fallback (deterministic across calls): K|Vt overlay the dead
        // attn_out region (16.78MB, written last); bitmask in dead W_K buffer
        // (packed AFTER k_projkv reads W_K); concat in dead mask buffer
        // (written AFTER k_pack reads mask).
        Kbuf   = (u16*)attn_out;
        Vtb    = Kbuf + (size_t)4194304;
        mbits  = (u64*)d_in[3];
        concat = (u16*)d_in[9];
    }

    k_projkv<<<dim3(64, 16), 256, 0, stream>>>(x, WK, bK, WV, bV, Kbuf, Vtb);
    k_pack<<<dim3(4096), 256, 0, stream>>>(mask, mbits);
    k_fused<<<dim3(32, 32), 256, 0, stream>>>(x, WQ, bQ, Kbuf, Vtb, mbits, sc, concat);
    k_out<<<dim3(64, 16), 256, 0, stream>>>(concat, WP, bP, attn_out);
}

// Round 3
// 804.462 us; speedup vs baseline: 1.5104x; 1.0614x over previous
//
#include <hip/hip_runtime.h>

// B=2, S=2048, D=1024, H=16, Khid=64.  Inputs/outputs f32; MFMA compute bf16.
typedef unsigned short u16;
typedef unsigned int u32;
typedef unsigned long long u64;
typedef __attribute__((ext_vector_type(8))) short short8;   // 8 bf16 (4 VGPRs)
typedef __attribute__((ext_vector_type(8))) float float8;   // 32B
typedef __attribute__((ext_vector_type(4))) float floatx4;  // MFMA accumulator

__device__ __forceinline__ u16 f2bf(float f) {
    unsigned u = __float_as_uint(f);
    return (u16)((u + 0x7FFFu + ((u >> 16) & 1u)) >> 16);  // RNE
}

#define MFMA(a, b, c) __builtin_amdgcn_mfma_f32_16x16x32_bf16((a), (b), (c), 0, 0, 0)

// Padded LDS strides (u16 units): b128 frag reads balanced (8 dwords/bank).
#define AST 40
#define KST 72
#define C2 0.18033688011112043f   // 0.125 * log2(e): softmax in exp2 domain

// ---------------------------------------------------------------------------
// Weight pre-transpose (one launch): slots 0..2 = W_Q/K/V [16][1024][64] f32
// -> wt3[slot][h][n][1024d] bf16; slot 3 = W_proj [1024][1024] -> wpT[n][c] bf16.
// grid (2048) x 256.  Reads are scattered (L2-absorbed, one-shot); writes coalesced.
__global__ __launch_bounds__(256) void k_wtall(
    const float* __restrict__ wq, const float* __restrict__ wk,
    const float* __restrict__ wv, const float* __restrict__ wp,
    u16* __restrict__ wt3, u16* __restrict__ wpT)
{
    int slot = blockIdx.x >> 9;
    int id = (blockIdx.x & 511) * 256 + threadIdx.x;
    const float* in; u16* out; int logC;
    if (slot == 3) { in = wp; out = wpT; logC = 10; }
    else {
        in = (slot == 0) ? wq : (slot == 1 ? wk : wv);
        out = wt3 + (size_t)slot * 1048576;
        logC = 6;
    }
    int rg = id & 127;            // r0 = rg*8, R = 1024
    int rest = id >> 7;
    int C = 1 << logC;
    int cc = rest & (C - 1);
    int bt = rest >> logC;
    const float* src = in + ((size_t)bt << (10 + logC)) + cc;
    int r0 = rg * 8;
    short8 o;
    #pragma unroll
    for (int j = 0; j < 8; j++) o[j] = (short)f2bf(src[(size_t)(r0 + j) << logC]);
    *(short8*)&out[(((size_t)bt << logC) + cc) * 1024 + r0] = o;
}

// ---------------------------------------------------------------------------
// Merged Q+K+V projection. Q,K -> [bh][s][64] bf16; V^T -> [bh][n][2048] bf16.
// One shared x A-tile, 12 MFMA/round. If wtT != null, B-staging is conflict-free
// short8 row copies from pre-transposed bf16 weights. grid (64, 16) x 256
__global__ __launch_bounds__(256) void k_projqkv(
    const float* __restrict__ x,
    const float* __restrict__ wq, const float* __restrict__ bq,
    const float* __restrict__ wk, const float* __restrict__ bk,
    const float* __restrict__ wv, const float* __restrict__ bv,
    const u16* __restrict__ wtT,          // [3][16][64][1024] bf16 or null
    u16* __restrict__ Qout, u16* __restrict__ Kout, u16* __restrict__ Vout)
{
    int mt = blockIdx.x, h = blockIdx.y;
    int tid = threadIdx.x, wave = tid >> 6, lane = tid & 63;
    int col = lane & 15, quad = lane >> 4, m0 = wave * 16;
    int rg0 = mt * 64;
    bool doQ = (Qout != nullptr);

    __shared__ __align__(16) char pool[4 * 64 * AST * 2];   // As,Bq,Bk,Bv 20480B
    u16* As = (u16*)pool;
    u16* Bq = As + 64 * AST;
    u16* Bk = Bq + 64 * AST;
    u16* Bv = Bk + 64 * AST;

    floatx4 aQ[4], aK[4], aV[4];
    for (int i = 0; i < 4; i++) { aQ[i] = (floatx4){0,0,0,0}; aK[i] = (floatx4){0,0,0,0}; aV[i] = (floatx4){0,0,0,0}; }

    int lr = tid >> 2, lc = (tid & 3) * 8;   // As staging: 64 s x 32 d
    float8 av = *(const float8*)&x[(size_t)(rg0 + lr) * 1024 + lc];

    if (wtT) {
        const u16* wqT = wtT + ((size_t)h * 64) * 1024;
        const u16* wkT = wqT + 1048576;
        const u16* wvT = wkT + 1048576;
        int nr = tid >> 2, dc = (tid & 3) * 8;   // B staging: 64 n x 32 d rows
        short8 q8 = *(const short8*)&wqT[(size_t)nr * 1024 + dc];
        short8 k8 = *(const short8*)&wkT[(size_t)nr * 1024 + dc];
        short8 v8 = *(const short8*)&wvT[(size_t)nr * 1024 + dc];
        for (int dk = 0; dk < 1024; dk += 32) {
            short8 a8;
            #pragma unroll
            for (int j = 0; j < 8; j++) a8[j] = (short)f2bf(av[j]);
            *(short8*)&As[lr * AST + lc] = a8;
            *(short8*)&Bq[nr * AST + dc] = q8;
            *(short8*)&Bk[nr * AST + dc] = k8;
            *(short8*)&Bv[nr * AST + dc] = v8;
            __syncthreads();
            if (dk + 32 < 1024) {
                av = *(const float8*)&x[(size_t)(rg0 + lr) * 1024 + dk + 32 + lc];
                q8 = *(const short8*)&wqT[(size_t)nr * 1024 + dk + 32 + dc];
                k8 = *(const short8*)&wkT[(size_t)nr * 1024 + dk + 32 + dc];
                v8 = *(const short8*)&wvT[(size_t)nr * 1024 + dk + 32 + dc];
            }
            short8 a = *(const short8*)&As[(m0 + col) * AST + quad * 8];
            #pragma unroll
            for (int nt = 0; nt < 4; nt++) {
                short8 fq = *(const short8*)&Bq[(nt * 16 + col) * AST + quad * 8];
                short8 fk = *(const short8*)&Bk[(nt * 16 + col) * AST + quad * 8];
                short8 fv = *(const short8*)&Bv[(nt * 16 + col) * AST + quad * 8];
                if (doQ) aQ[nt] = MFMA(a, fq, aQ[nt]);
                aK[nt] = MFMA(a, fk, aK[nt]);
                aV[nt] = MFMA(a, fv, aV[nt]);
            }
            __syncthreads();
        }
    } else {
        // f32-weight path (fallback): transpose staging (slower, correct)
        int dr = tid >> 3, nc = (tid & 7) * 8;
        const float* whq = wq + (size_t)h * 65536;
        const float* whk = wk + (size_t)h * 65536;
        const float* whv = wv + (size_t)h * 65536;
        float8 qp = *(const float8*)&whq[(size_t)dr * 64 + nc];
        float8 kp = *(const float8*)&whk[(size_t)dr * 64 + nc];
        float8 vp = *(const float8*)&whv[(size_t)dr * 64 + nc];
        for (int dk = 0; dk < 1024; dk += 32) {
            short8 a8;
            #pragma unroll
            for (int j = 0; j < 8; j++) a8[j] = (short)f2bf(av[j]);
            *(short8*)&As[lr * AST + lc] = a8;
            #pragma unroll
            for (int j = 0; j < 8; j++) Bk[(nc + j) * AST + dr] = f2bf(kp[j]);
            #pragma unroll
            for (int j = 0; j < 8; j++) Bv[(nc + j) * AST + dr] = f2bf(vp[j]);
            if (doQ) {
                #pragma unroll
                for (int j = 0; j < 8; j++) Bq[(nc + j) * AST + dr] = f2bf(qp[j]);
            }
            __syncthreads();
            if (dk + 32 < 1024) {
                av = *(const float8*)&x[(size_t)(rg0 + lr) * 1024 + dk + 32 + lc];
                qp = *(const float8*)&whq[(size_t)(dk + 32 + dr) * 64 + nc];
                kp = *(const float8*)&whk[(size_t)(dk + 32 + dr) * 64 + nc];
                vp = *(const float8*)&whv[(size_t)(dk + 32 + dr) * 64 + nc];
            }
            short8 a = *(const short8*)&As[(m0 + col) * AST + quad * 8];
            #pragma unroll
            for (int nt = 0; nt < 4; nt++) {
                short8 fk = *(const short8*)&Bk[(nt * 16 + col) * AST + quad * 8];
                short8 fv = *(const short8*)&Bv[(nt * 16 + col) * AST + quad * 8];
                aK[nt] = MFMA(a, fk, aK[nt]);
                aV[nt] = MFMA(a, fv, aV[nt]);
                if (doQ) {
                    short8 fq = *(const short8*)&Bq[(nt * 16 + col) * AST + quad * 8];
                    aQ[nt] = MFMA(a, fq, aQ[nt]);
                }
            }
            __syncthreads();
        }
    }

    int bb = rg0 >> 11, s0b = rg0 & 2047;
    size_t bh = (size_t)(bb * 16 + h);

    #pragma unroll
    for (int nt = 0; nt < 4; nt++) {
        int n = nt * 16 + col;
        float bkl = bk[h * 64 + n];
        #pragma unroll
        for (int r = 0; r < 4; r++) {
            int rowl = m0 + quad * 4 + r;
            Kout[(bh * 2048 + s0b + rowl) * 64 + n] = f2bf(aK[nt][r] + bkl);
        }
    }
    if (doQ) {
        #pragma unroll
        for (int nt = 0; nt < 4; nt++) {
            int n = nt * 16 + col;
            float bql = bq[h * 64 + n];
            #pragma unroll
            for (int r = 0; r < 4; r++) {
                int rowl = m0 + quad * 4 + r;
                Qout[(bh * 2048 + s0b + rowl) * 64 + n] = f2bf(aQ[nt][r] + bql);
            }
        }
    }
    // V: LDS transpose -> coalesced 32B/lane rows
    u16* VT = (u16*)pool;   // [64 n][stride 68] = 8704B
    #pragma unroll
    for (int nt = 0; nt < 4; nt++) {
        int n = nt * 16 + col;
        float bvl = bv[h * 64 + n];
        #pragma unroll
        for (int r = 0; r < 4; r++) {
            int rowl = m0 + quad * 4 + r;
            VT[n * 68 + rowl] = f2bf(aV[nt][r] + bvl);
        }
    }
    __syncthreads();
    {
        int n2 = tid >> 2, sseg = (tid & 3) * 16;
        short8 p0 = *(const short8*)&VT[n2 * 68 + sseg];
        short8 p1 = *(const short8*)&VT[n2 * 68 + sseg + 8];
        u16* dst = &Vout[(bh * 64 + n2) * 2048 + s0b + sseg];
        *(short8*)dst = p0;
        *(short8*)(dst + 8) = p1;
    }
}

// ---------------------------------------------------------------------------
// Pack mask [2,2048,2048] i32 -> transposed bitmask bits[(b*32+w)*2048+s].
__global__ __launch_bounds__(256) void k_pack(
    const int* __restrict__ mask, u64* __restrict__ bits)
{
    int row = blockIdx.x;              // b*2048 + s
    int b = row >> 11, s = row & 2047;
    int wv = threadIdx.x >> 6, lane = threadIdx.x & 63;
    for (int w = wv; w < 32; w += 4) {
        int m = mask[(size_t)row * 2048 + w * 64 + lane];
        u64 bal = __ballot(m != 0);
        if (lane == 0) bits[((size_t)(b * 32 + w)) * 2048 + s] = bal;
    }
}

// ---------------------------------------------------------------------------
// Fused scores+softmax+PV. Q from Qbuf (or computed in-kernel if Qbuf==null).
// Pass 1: swapped QK^T, TBLK=128, per-lane running (m,l) in exp2 domain.
// Pass 2: normal-orientation recompute, p=exp2(s2-m2)/l, write p, PV -> concat.
// grid (32, 32) x 256
__global__ __launch_bounds__(256, 4) void k_fused(
    const float* __restrict__ x, const float* __restrict__ wq, const float* __restrict__ bq,
    const u16* __restrict__ Qbuf, const u16* __restrict__ Kbuf, const u16* __restrict__ Vt,
    const u64* __restrict__ mbits,
    float* __restrict__ sc, u16* __restrict__ concat)
{
    int st = blockIdx.x, bh = blockIdx.y;
    int b = bh >> 4, h = bh & 15;
    int s0 = st * 64;
    int tid = threadIdx.x, wave = tid >> 6, lane = tid & 63;
    int col = lane & 15, quad = lane >> 4, m0 = wave * 16;

    __shared__ __align__(16) char pool[3 * 64 * KST * 2];   // 27648B
    u16* Ks = (u16*)pool;                       // pass2 K tile [64t][64]
    u16* Vs = (u16*)(pool + 64 * KST * 2);      // pass2 V tile [64n][64t]
    u16* Ps = (u16*)(pool + 2 * 64 * KST * 2);  // Q tile / pass2 P tile
    u16* K128 = Ks;                             // pass1 K tile [128t][64] (Ks+Vs)
    __shared__ u64 Mw[128];
    __shared__ float mrun[64], lrun[64];

    // ---- Q tile -> Ps ----
    if (Qbuf) {
        const u16* Qh = Qbuf + (size_t)bh * 2048 * 64;
        int qr = tid >> 2, qc = (tid & 3) * 16;
        *(short8*)&Ps[qr * KST + qc]     = *(const short8*)&Qh[(size_t)(s0 + qr) * 64 + qc];
        *(short8*)&Ps[qr * KST + qc + 8] = *(const short8*)&Qh[(size_t)(s0 + qr) * 64 + qc + 8];
        __syncthreads();
    } else {
        // fallback: compute Q on the fly (round-2 phase 0)
        floatx4 acc[4];
        for (int i = 0; i < 4; i++) acc[i] = (floatx4){0,0,0,0};
        int lr = tid >> 2, lc = (tid & 3) * 8;
        int dr = tid >> 3, nc = (tid & 7) * 8;
        const float* wh = wq + (size_t)h * 65536;
        const float* xb = x + ((size_t)b * 2048 + s0) * 1024;
        u16* As = Ks; u16* Bs = Vs;
        float8 av = *(const float8*)&xb[(size_t)lr * 1024 + lc];
        float8 wv = *(const float8*)&wh[(size_t)dr * 64 + nc];
        for (int dk = 0; dk < 1024; dk += 32) {
            short8 a8;
            #pragma unroll
            for (int j = 0; j < 8; j++) a8[j] = (short)f2bf(av[j]);
            *(short8*)&As[lr * AST + lc] = a8;
            #pragma unroll
            for (int j = 0; j < 8; j++) Bs[(nc + j) * AST + dr] = f2bf(wv[j]);
            __syncthreads();
            if (dk + 32 < 1024) {
                av = *(const float8*)&xb[(size_t)lr * 1024 + dk + 32 + lc];
                wv = *(const float8*)&wh[(size_t)(dk + 32 + dr) * 64 + nc];
            }
            short8 a = *(const short8*)&As[(m0 + col) * AST + quad * 8];
            #pragma unroll
            for (int nt = 0; nt < 4; nt++) {
                short8 b2 = *(const short8*)&Bs[(nt * 16 + col) * AST + quad * 8];
                acc[nt] = MFMA(a, b2, acc[nt]);
            }
            __syncthreads();
        }
        #pragma unroll
        for (int nt = 0; nt < 4; nt++) {
            int n = nt * 16 + col;
            float bvq = bq[h * 64 + n];
            #pragma unroll
            for (int r = 0; r < 4; r++) {
                int rowl = m0 + quad * 4 + r;
                Ps[rowl * KST + n] = f2bf(acc[nt][r] + bvq);
            }
        }
        __syncthreads();
    }
    short8 aq0 = *(const short8*)&Ps[(m0 + col) * KST + quad * 8];
    short8 aq1 = *(const short8*)&Ps[(m0 + col) * KST + 32 + quad * 8];

    const u16* Kh = Kbuf + (size_t)bh * 2048 * 64;
    const u16* Vh = Vt + (size_t)bh * 64 * 2048;
    const u64* mrow = mbits + (size_t)b * 32 * 2048;
    int qs4 = quad * 4;

    // ---- Pass 1: stats only (swapped, TBLK=128, exp2-domain register softmax) ----
    float mreg = -1e30f, lreg = 0.f;   // stats for s-row = s0 + m0 + col
    {
        int r0 = tid >> 1, c0 = (tid & 1) * 32;
        short8 kp[4];
        #pragma unroll
        for (int j = 0; j < 4; j++) kp[j] = *(const short8*)&Kh[(size_t)r0 * 64 + c0 + j * 8];
        for (int t0 = 0; t0 < 2048; t0 += 128) {
            #pragma unroll
            for (int j = 0; j < 4; j++) *(short8*)&K128[r0 * KST + c0 + j * 8] = kp[j];
            if (tid < 128) Mw[tid] = mrow[(size_t)((t0 >> 6) + (tid >> 6)) * 2048 + s0 + (tid & 63)];
            __syncthreads();
            if (t0 + 128 < 2048) {
                #pragma unroll
                for (int j = 0; j < 4; j++) kp[j] = *(const short8*)&Kh[(size_t)(t0 + 128 + r0) * 64 + c0 + j * 8];
            }
            #pragma unroll
            for (int half = 0; half < 2; half++) {
                floatx4 c4[4];
                #pragma unroll
                for (int tt = 0; tt < 4; tt++) {
                    c4[tt] = (floatx4){0,0,0,0};
                    int trow = (half * 4 + tt) * 16 + col;
                    short8 b0 = *(const short8*)&K128[trow * KST + quad * 8];
                    short8 b1 = *(const short8*)&K128[trow * KST + 32 + quad * 8];
                    c4[tt] = MFMA(b0, aq0, c4[tt]);   // D[t][s]: t lane-local
                    c4[tt] = MFMA(b1, aq1, c4[tt]);
                }
                u64 w = Mw[half * 64 + m0 + col];
                u32 blo = ((u32)w) >> qs4;
                u32 bhi = ((u32)(w >> 32)) >> qs4;
                float v[16];
                float tmax = -1e30f;
                #pragma unroll
                for (int tt = 0; tt < 4; tt++) {
                    u32 bsel = (tt < 2) ? blo : bhi;
                    #pragma unroll
                    for (int r = 0; r < 4; r++) {
                        bool on = (bsel >> ((tt & 1) * 16 + r)) & 1u;
                        float vv = on ? c4[tt][r] * C2 : -1e30f;
                        v[tt * 4 + r] = vv;
                        tmax = fmaxf(tmax, vv);
                    }
                }
                float nm = fmaxf(mreg, tmax);
                lreg *= exp2f(mreg - nm);
                float ss = 0.f;
                #pragma unroll
                for (int i = 0; i < 16; i++) ss += exp2f(v[i] - nm);   // masked -> +0
                lreg += ss;
                mreg = nm;
            }
            __syncthreads();
        }
    }
    // merge (m,l) across the 4 quads holding the same s-row
    {
        float mo = __shfl_xor(mreg, 16, 64), lx = __shfl_xor(lreg, 16, 64);
        float nm = fmaxf(mreg, mo);
        lreg = lreg * exp2f(mreg - nm) + lx * exp2f(mo - nm); mreg = nm;
        mo = __shfl_xor(mreg, 32, 64); lx = __shfl_xor(lreg, 32, 64);
        nm = fmaxf(mreg, mo);
        lreg = lreg * exp2f(mreg - nm) + lx * exp2f(mo - nm); mreg = nm;
    }
    if (quad == 0) { mrun[m0 + col] = mreg; lrun[m0 + col] = lreg; }
    __syncthreads();

    // ---- Pass 2: recompute (normal orientation), normalize, write p, PV ----
    float mr4[4], rl4[4];
    #pragma unroll
    for (int r = 0; r < 4; r++) {
        int rowl = m0 + qs4 + r;
        mr4[r] = mrun[rowl];
        rl4[r] = 1.0f / lrun[rowl];   // l >= 1 always
    }
    floatx4 accp[4];
    for (int i = 0; i < 4; i++) accp[i] = (floatx4){0,0,0,0};
    float* scb = sc + (size_t)bh * 4194304;
    {
        int srow = tid >> 3, soff = (tid & 7) * 8;
        short8 kp0 = *(const short8*)&Kh[(size_t)srow * 64 + soff];
        short8 kp1 = *(const short8*)&Kh[(size_t)(srow + 32) * 64 + soff];
        short8 vp0 = *(const short8*)&Vh[(size_t)srow * 2048 + soff];
        short8 vp1 = *(const short8*)&Vh[(size_t)(srow + 32) * 2048 + soff];
        for (int t0 = 0; t0 < 2048; t0 += 64) {
            *(short8*)&Ks[srow * KST + soff]        = kp0;
            *(short8*)&Ks[(srow + 32) * KST + soff] = kp1;
            *(short8*)&Vs[srow * KST + soff]        = vp0;
            *(short8*)&Vs[(srow + 32) * KST + soff] = vp1;
            if (tid < 64) Mw[tid] = mrow[(size_t)(t0 >> 6) * 2048 + s0 + tid];
            __syncthreads();
            if (t0 + 64 < 2048) {
                kp0 = *(const short8*)&Kh[(size_t)(t0 + 64 + srow) * 64 + soff];
                kp1 = *(const short8*)&Kh[(size_t)(t0 + 64 + srow + 32) * 64 + soff];
                vp0 = *(const short8*)&Vh[(size_t)srow * 2048 + t0 + 64 + soff];
                vp1 = *(const short8*)&Vh[(size_t)(srow + 32) * 2048 + t0 + 64 + soff];
            }
            floatx4 c4[4];
            #pragma unroll
            for (int nt = 0; nt < 4; nt++) {
                c4[nt] = (floatx4){0,0,0,0};
                short8 b0 = *(const short8*)&Ks[(nt * 16 + col) * KST + quad * 8];
                short8 b1 = *(const short8*)&Ks[(nt * 16 + col) * KST + 32 + quad * 8];
                c4[nt] = MFMA(aq0, b0, c4[nt]);
                c4[nt] = MFMA(aq1, b1, c4[nt]);
            }
            #pragma unroll
            for (int r = 0; r < 4; r++) {
                int rowl = m0 + qs4 + r;
                u64 w = Mw[rowl];
                u32 blo = ((u32)w) >> col;
                u32 bhi = ((u32)(w >> 32)) >> col;
                size_t base = (size_t)(s0 + rowl) * 2048 + t0;
                #pragma unroll
                for (int nt = 0; nt < 4; nt++) {
                    u32 bsel = (nt < 2) ? blo : bhi;
                    bool on = (bsel >> ((nt & 1) * 16)) & 1u;
                    float s2 = on ? c4[nt][r] * C2 : -1e30f;
                    float p = exp2f(s2 - mr4[r]) * rl4[r];   // masked -> +0
                    scb[base + nt * 16 + col] = p;
                    Ps[rowl * KST + nt * 16 + col] = f2bf(p);
                }
            }
            __syncthreads();
            short8 ap0 = *(const short8*)&Ps[(m0 + col) * KST + quad * 8];
            short8 ap1 = *(const short8*)&Ps[(m0 + col) * KST + 32 + quad * 8];
            #pragma unroll
            for (int nt = 0; nt < 4; nt++) {
                short8 b0 = *(const short8*)&Vs[(nt * 16 + col) * KST + quad * 8];
                short8 b1 = *(const short8*)&Vs[(nt * 16 + col) * KST + 32 + quad * 8];
                accp[nt] = MFMA(ap0, b0, accp[nt]);
                accp[nt] = MFMA(ap1, b1, accp[nt]);
            }
            __syncthreads();
        }
    }
    #pragma unroll
    for (int nt = 0; nt < 4; nt++) {
        int n = nt * 16 + col;
        #pragma unroll
        for (int r = 0; r < 4; r++) {
            int rowl = m0 + qs4 + r;
            concat[((size_t)(b * 2048 + s0 + rowl)) * 1024 + h * 64 + n] = f2bf(accp[nt][r]);
        }
    }
}

// ---------------------------------------------------------------------------
// Output projection: out f32 = concat(bf16) @ W_proj + b_proj.  grid (64,16) x 256
__global__ __launch_bounds__(256) void k_out(
    const u16* __restrict__ concat, const float* __restrict__ wp,
    const u16* __restrict__ wpT, const float* __restrict__ bp,
    float* __restrict__ outp)
{
    int mt = blockIdx.x, ntile = blockIdx.y;
    int n0 = ntile * 64;
    int tid = threadIdx.x, wave = tid >> 6, lane = tid & 63;
    int col = lane & 15, quad = lane >> 4, m0 = wave * 16;
    int rg0 = mt * 64;

    __shared__ u16 As[64 * AST];
    __shared__ u16 Bs[64 * AST];

    floatx4 acc[4];
    for (int i = 0; i < 4; i++) acc[i] = (floatx4){0,0,0,0};

    int lr = tid >> 2, lc = (tid & 3) * 8;
    short8 ap = *(const short8*)&concat[(size_t)(rg0 + lr) * 1024 + lc];
    if (wpT) {
        int nr = tid >> 2, dc = (tid & 3) * 8;
        short8 w8 = *(const short8*)&wpT[(size_t)(n0 + nr) * 1024 + dc];
        for (int c = 0; c < 1024; c += 32) {
            *(short8*)&As[lr * AST + lc] = ap;
            *(short8*)&Bs[nr * AST + dc] = w8;
            __syncthreads();
            if (c + 32 < 1024) {
                ap = *(const short8*)&concat[(size_t)(rg0 + lr) * 1024 + c + 32 + lc];
                w8 = *(const short8*)&wpT[(size_t)(n0 + nr) * 1024 + c + 32 + dc];
            }
            short8 a = *(const short8*)&As[(m0 + col) * AST + quad * 8];
            #pragma unroll
            for (int nt = 0; nt < 4; nt++) {
                short8 bf = *(const short8*)&Bs[(nt * 16 + col) * AST + quad * 8];
                acc[nt] = MFMA(a, bf, acc[nt]);
            }
            __syncthreads();
        }
    } else {
        int cr = tid >> 3, nc = (tid & 7) * 8;
        float8 wv = *(const float8*)&wp[(size_t)cr * 1024 + n0 + nc];
        for (int c = 0; c < 1024; c += 32) {
            *(short8*)&As[lr * AST + lc] = ap;
            #pragma unroll
            for (int j = 0; j < 8; j++) Bs[(nc + j) * AST + cr] = f2bf(wv[j]);
            __syncthreads();
            if (c + 32 < 1024) {
                ap = *(const short8*)&concat[(size_t)(rg0 + lr) * 1024 + c + 32 + lc];
                wv = *(const float8*)&wp[(size_t)(c + 32 + cr) * 1024 + n0 + nc];
            }
            short8 a = *(const short8*)&As[(m0 + col) * AST + quad * 8];
            #pragma unroll
            for (int nt = 0; nt < 4; nt++) {
                short8 bf = *(const short8*)&Bs[(nt * 16 + col) * AST + quad * 8];
                acc[nt] = MFMA(a, bf, acc[nt]);
            }
            __syncthreads();
        }
    }
    #pragma unroll
    for (int nt = 0; nt < 4; nt++) {
        int n = n0 + nt * 16 + col;
        float bv = bp[n];
        #pragma unroll
        for (int r = 0; r < 4; r++) {
            int rowl = m0 + quad * 4 + r;
            outp[(size_t)(rg0 + rowl) * 1024 + n] = acc[nt][r] + bv;
        }
    }
}

// ---------------------------------------------------------------------------
extern "C" void kernel_launch(void* const* d_in, const int* in_sizes, int n_in,
                              void* d_out, int out_size, void* d_ws, size_t ws_size,
                              hipStream_t stream) {
    const float* x  = (const float*)d_in[0];
    const float* WQ = (const float*)d_in[1];
    const float* bQ = (const float*)d_in[2];
    const float* WK = (const float*)d_in[3];
    const float* bK = (const float*)d_in[4];
    const float* WV = (const float*)d_in[5];
    const float* bV = (const float*)d_in[6];
    const float* WP = (const float*)d_in[7];
    const float* bP = (const float*)d_in[8];
    const int* mask = (const int*)d_in[9];

    float* out = (float*)d_out;
    float* attn_out = out;                     // [2,2048,1024] f32
    float* sc = out + (size_t)4194304;         // [2,16,2048,2048] f32

    const size_t NEED_BIG = (size_t)4 * 8388608 + 1048576 + 6291456 + 2097152; // 42.99MB
    const size_t NEED_MID = (size_t)3 * 8388608 + 1048576;                     // 26.2MB
    u16 *Kbuf, *Vtb, *Qbuf = nullptr, *concat, *wt3 = nullptr, *wpT = nullptr;
    u64* mbits;
    if (ws_size >= NEED_BIG) {
        char* ws = (char*)d_ws;
        Kbuf   = (u16*)ws;   ws += 8388608;
        Vtb    = (u16*)ws;   ws += 8388608;
        Qbuf   = (u16*)ws;   ws += 8388608;
        concat = (u16*)ws;   ws += 8388608;
        mbits  = (u64*)ws;   ws += 1048576;
        wt3    = (u16*)ws;   ws += 6291456;
        wpT    = (u16*)ws;
    } else if (ws_size >= NEED_MID) {
        char* ws = (char*)d_ws;
        Kbuf   = (u16*)ws;   ws += 8388608;
        Vtb    = (u16*)ws;   ws += 8388608;
        concat = (u16*)ws;   ws += 8388608;
        mbits  = (u64*)ws;
    } else {
        // Fallback: K|Vt overlay dead attn_out; mbits in dead W_K (packed
        // after k_projqkv reads W_K); concat in dead mask (after k_pack).
        Kbuf   = (u16*)attn_out;
        Vtb    = Kbuf + (size_t)4194304;
        mbits  = (u64*)d_in[3];
        concat = (u16*)d_in[9];
    }

    if (wt3)
        k_wtall<<<dim3(2048), 256, 0, stream>>>(WQ, WK, WV, WP, wt3, wpT);
    k_projqkv<<<dim3(64, 16), 256, 0, stream>>>(x, WQ, bQ, WK, bK, WV, bV,
                                                wt3, Qbuf, Kbuf, Vtb);
    k_pack<<<dim3(4096), 256, 0, stream>>>(mask, mbits);
    k_fused<<<dim3(32, 32), 256, 0, stream>>>(x, WQ, bQ, Qbuf, Kbuf, Vtb, mbits, sc, concat);
    k_out<<<dim3(64, 16), 256, 0, stream>>>(concat, WP, wpT, bP, attn_out);
}